// Round 4
// baseline (46284.811 us; speedup 1.0000x reference)
//
#include <hip/hip_runtime.h>
#include <math.h>

#define B 64
#define T_READ 128
#define L_WRITE 32
#define TT 160
#define D 256
#define R 1024
#define N 512
#define M 128
#define HD 524
#define K5K 1152
#define EPS 1e-8f
#define NBLK 256
#define NTHR 512

__device__ __forceinline__ float sigmoidf(float x){ return 1.0f/(1.0f+expf(-x)); }
__device__ __forceinline__ float softplusf(float x){ return (x > 20.f) ? x : log1pf(expf(x)); }

// ---------- one-time: transpose x -> xT[t][k][b] ----------
__global__ __launch_bounds__(256) void kx_transpose(const float* __restrict__ x, float* __restrict__ xT){
    __shared__ float tile[64][65];
    const int t = blockIdx.x >> 2, k0 = (blockIdx.x & 3)*64;
    #pragma unroll
    for (int rep = 0; rep < 16; ++rep){
        int idx = rep*256 + threadIdx.x;
        int bl = idx >> 6, kl = idx & 63;
        tile[bl][kl] = x[((size_t)bl*T_READ + t)*D + k0 + kl];
    }
    __syncthreads();
    #pragma unroll
    for (int rep = 0; rep < 16; ++rep){
        int idx = rep*256 + threadIdx.x;
        int kl = idx >> 6, bl = idx & 63;
        xT[((size_t)t*D + k0 + kl)*64 + bl] = tile[bl][kl];
    }
}

// ---------- one-time: init all state + barrier counters ----------
__global__ void k_init(float* a_all, float* c_t, float* w_r, float* w_w, float* Mem, unsigned* bar){
    int idx = blockIdx.x*blockDim.x + threadIdx.x;
    int stride = gridDim.x*blockDim.x;
    for (int i = idx; i < B*N*M; i += stride) Mem[i] = 1e-6f;
    for (int i = idx; i < (1408-256)*64; i += stride) a_all[256*64 + i] = 0.f;
    for (int i = idx; i < R*64; i += stride) c_t[i] = 0.f;
    for (int i = idx; i < B*N; i += stride){ w_r[i] = 1.f/512.f; w_w[i] = 1.f/512.f; }
    if (idx == 0){ bar[0] = 0u; bar[1] = 0u; }
}

// ---------- device-scope grid barrier (one arrival per block) ----------
__device__ __forceinline__ void gbar(unsigned* bar){
    __syncthreads();
    if (threadIdx.x == 0){
        __threadfence();
        unsigned g = __hip_atomic_load(&bar[1], __ATOMIC_RELAXED, __HIP_MEMORY_SCOPE_AGENT);
        unsigned a = __hip_atomic_fetch_add(&bar[0], 1u, __ATOMIC_ACQ_REL, __HIP_MEMORY_SCOPE_AGENT);
        if (a == (unsigned)(NBLK-1)){
            __hip_atomic_store(&bar[0], 0u, __ATOMIC_RELAXED, __HIP_MEMORY_SCOPE_AGENT);
            __hip_atomic_store(&bar[1], g+1u, __ATOMIC_RELEASE, __HIP_MEMORY_SCOPE_AGENT);
        } else {
            while (__hip_atomic_load(&bar[1], __ATOMIC_ACQUIRE, __HIP_MEMORY_SCOPE_AGENT) == g){
                __builtin_amdgcn_s_sleep(2);
            }
        }
        __threadfence();
    }
    __syncthreads();
}

__device__ __forceinline__ float blk_sum8(float v, volatile float* red8, int lane, int wv){
    #pragma unroll
    for (int off = 32; off; off >>= 1) v += __shfl_xor(v, off);
    if (lane == 0) red8[wv] = v;
    __syncthreads();
    float r = red8[0]+red8[1]+red8[2]+red8[3]+red8[4]+red8[5]+red8[6]+red8[7];
    __syncthreads();
    return r;
}
__device__ __forceinline__ float blk_max8(float v, volatile float* red8, int lane, int wv){
    #pragma unroll
    for (int off = 32; off; off >>= 1) v = fmaxf(v, __shfl_xor(v, off));
    if (lane == 0) red8[wv] = v;
    __syncthreads();
    float r = fmaxf(fmaxf(fmaxf(red8[0],red8[1]),fmaxf(red8[2],red8[3])),
                    fmaxf(fmaxf(red8[4],red8[5]),fmaxf(red8[6],red8[7])));
    __syncthreads();
    return r;
}

// ---------- persistent kernel: all 160 steps + batched output GEMM ----------
__global__ __launch_bounds__(NTHR, 1) void k_persist(
    const float* __restrict__ xT, const float* __restrict__ Wl, const float* __restrict__ Ul,
    const float* __restrict__ bl, const float* __restrict__ Wh, const float* __restrict__ bh,
    const float* __restrict__ Wo, const float* __restrict__ bo,
    float* __restrict__ a_all, float* __restrict__ c_t,
    float* __restrict__ khat, float* __restrict__ scal, float* __restrict__ ea,
    float* __restrict__ mnorm, float* __restrict__ dots,
    float* __restrict__ w_r, float* __restrict__ w_w,
    float* __restrict__ Mem, float* __restrict__ hist,
    float* __restrict__ out, unsigned* __restrict__ bar)
{
    __shared__ float smem[16384];   // 64 KB, reused per stage
    const int bk   = blockIdx.x;
    const int tid  = threadIdx.x;
    const int lane = tid & 63;
    const int w    = tid >> 6;

    for (int t = 0; t < TT; ++t){
        // ======== S1: z = W·[x_t, reads] + U·h + b, then LSTM gates ========
        {
            const int r0 = bk*4;
            const int kn = (t < T_READ) ? 176 : 144;
            const int k0 = (t < T_READ) ? w*176 : 256 + w*144;
            float acc[16];
            #pragma unroll
            for (int i = 0; i < 16; ++i) acc[i] = 0.f;
            #pragma unroll 4
            for (int kk = 0; kk < kn; ++kk){
                int k = k0 + kk;
                const float* ap = (k < 256) ? (xT + ((size_t)t*256 + k)*64) : (a_all + (size_t)k*64);
                float a = ap[lane];
                const float* wrow = (k < 384) ? (Wl + (size_t)k*4096) : (Ul + (size_t)(k-384)*4096);
                #pragma unroll
                for (int q = 0; q < 4; ++q){
                    float4 wv = *reinterpret_cast<const float4*>(wrow + q*1024 + r0);
                    acc[q*4+0] += a*wv.x; acc[q*4+1] += a*wv.y;
                    acc[q*4+2] += a*wv.z; acc[q*4+3] += a*wv.w;
                }
            }
            #pragma unroll
            for (int c = 0; c < 16; ++c) smem[(w*16 + c)*64 + lane] = acc[c];
            __syncthreads();
            if (tid < 256){
                int r_l = tid >> 6, b = tid & 63;
                float g4[4];
                #pragma unroll
                for (int q = 0; q < 4; ++q){
                    float s = bl[q*1024 + r0 + r_l];
                    #pragma unroll
                    for (int ks = 0; ks < 8; ++ks) s += smem[(ks*16 + q*4 + r_l)*64 + b];
                    g4[q] = s;
                }
                int ri = (r0 + r_l)*64 + b;
                float cn = sigmoidf(g4[1])*c_t[ri] + sigmoidf(g4[0])*tanhf(g4[2]);
                float hn = sigmoidf(g4[3])*tanhf(cn);
                c_t[ri] = cn;
                a_all[(size_t)(384 + r0 + r_l)*64 + b] = hn;
                if (t >= T_READ) hist[((size_t)(t-T_READ)*K5K + r0 + r_l)*64 + b] = hn;
            }
        }
        gbar(bar);

        // ======== S2: head params p = Wh·h + bh, finalize khat/scal/ea ========
        {
            const int c0 = bk*2;
            const int ncols = (bk < 12) ? 3 : 2;
            const int c2 = (bk < 12) ? (512 + bk) : 0;
            float a0 = 0.f, a1 = 0.f, a2 = 0.f;
            const int k0 = w*128;
            #pragma unroll 4
            for (int kk = 0; kk < 128; ++kk){
                int k = k0 + kk;
                float a = a_all[(size_t)(384 + k)*64 + lane];
                a0 += a * Wh[(size_t)k*HD + c0];
                a1 += a * Wh[(size_t)k*HD + c0 + 1];
                a2 += a * Wh[(size_t)k*HD + c2];
            }
            smem[(0*8 + w)*64 + lane] = a0;
            smem[(1*8 + w)*64 + lane] = a1;
            smem[(2*8 + w)*64 + lane] = a2;
            __syncthreads();
            if (tid < 192){
                int c = tid >> 6, b = tid & 63;
                if (c < ncols){
                    int j = (c < 2) ? (c0 + c) : (512 + bk);
                    float v = bh[j];
                    #pragma unroll
                    for (int ks = 0; ks < 8; ++ks) v += smem[(c*8 + ks)*64 + b];
                    if (j < 128)            khat[b*256 + j] = tanhf(v);
                    else if (j < 134){ int i = j-128; scal[b*12 + i]   = (i==0)?softplusf(v):(i==1)?sigmoidf(v):(i==5)?1.f+softplusf(v):v; }
                    else if (j < 262)       khat[b*256 + 128 + (j-134)] = tanhf(v);
                    else if (j < 268){ int i = j-262; scal[b*12 + 6+i] = (i==0)?softplusf(v):(i==1)?sigmoidf(v):(i==5)?1.f+softplusf(v):v; }
                    else if (j < 396)       ea[b*256 + (j-268)]         = sigmoidf(v);
                    else                    ea[b*256 + 128 + (j-396)]   = tanhf(v);
                }
            }
        }
        gbar(bar);

        // ======== S3: Mem row norms + content dots ========
        {
            const int b = bk >> 2, nq = bk & 3;
            float2 kr = *reinterpret_cast<const float2*>(khat + b*256 + lane*2);
            float2 kw = *reinterpret_cast<const float2*>(khat + b*256 + 128 + lane*2);
            #pragma unroll 2
            for (int i = 0; i < 16; ++i){
                int n = nq*128 + w*16 + i;
                const float* mrow = Mem + ((size_t)b*N + n)*M;
                float2 mv = *reinterpret_cast<const float2*>(mrow + lane*2);
                float s2 = mv.x*mv.x + mv.y*mv.y;
                float dr = mv.x*kr.x + mv.y*kr.y;
                float dw = mv.x*kw.x + mv.y*kw.y;
                #pragma unroll
                for (int off = 32; off; off >>= 1){
                    s2 += __shfl_xor(s2, off);
                    dr += __shfl_xor(dr, off);
                    dw += __shfl_xor(dw, off);
                }
                if (lane == 0){
                    mnorm[b*N + n] = sqrtf(s2);
                    dots[(b*2+0)*N + n] = dr;
                    dots[(b*2+1)*N + n] = dw;
                }
            }
        }
        gbar(bar);

        // ======== S4: addressing (blocks 0..127: one (b,head) each) ========
        if (bk < 128){
            volatile float* red8 = smem + 512;
            float* wg = smem;
            const int b = bk >> 1, head = bk & 1;
            const int n = tid;
            float kv = (n < 128) ? khat[b*256 + head*128 + n] : 0.f;
            float kn = sqrtf(blk_sum8(kv*kv, red8, lane, w));
            const float* sc = scal + b*12 + head*6;
            float beta = sc[0], gg = sc[1], gamma = sc[5];
            float s0r = sc[2], s1r = sc[3], s2r = sc[4];
            float smx = fmaxf(s0r, fmaxf(s1r, s2r));
            float e0 = expf(s0r-smx), e1 = expf(s1r-smx), e2 = expf(s2r-smx);
            float esum = e0+e1+e2;
            float s0 = e0/esum, s1 = e1/esum, s2 = e2/esum;

            float sim = dots[(b*2+head)*N + n] / (mnorm[b*N + n]*kn + EPS);
            float aa = beta * sim;
            float amax = blk_max8(aa, red8, lane, w);
            float ev = expf(aa - amax);
            float wc = ev / blk_sum8(ev, red8, lane, w);

            float* wbuf = head ? w_w : w_r;
            float wprev = wbuf[b*N + n];
            float wgv = gg*wc + (1.f - gg)*wprev;
            wg[n] = wgv; __syncthreads();
            float wsv = s0*wg[(n+1)&511] + s1*wgv + s2*wg[(n-1)&511];
            float wp = powf(wsv + EPS, gamma);
            float wsum = blk_sum8(wp, red8, lane, w);
            wbuf[b*N + n] = wp / wsum;
        }
        gbar(bar);

        // ======== S5: reads (old Mem) + erase/add update ========
        {
            const int b = bk >> 2, mg = bk & 3;
            smem[tid]       = w_r[b*N + tid];
            smem[512 + tid] = w_w[b*N + tid];
            const int m_l = tid & 31, ng = tid >> 5;
            const int m = mg*32 + m_l;
            const float e  = ea[b*256 + m];
            const float ad = ea[b*256 + 128 + m];
            __syncthreads();
            float racc = 0.f;
            #pragma unroll 4
            for (int i = 0; i < 32; ++i){
                int n = i*16 + ng;
                size_t idx = ((size_t)b*N + n)*M + m;
                float v = Mem[idx];
                float wr = smem[n], ww = smem[512 + n];
                racc += wr*v;
                Mem[idx] = v*(1.f - ww*e) + ww*ad;
            }
            __syncthreads();
            smem[1024 + tid] = racc;
            __syncthreads();
            if (tid < 32){
                float s = 0.f;
                #pragma unroll
                for (int g2 = 0; g2 < 16; ++g2) s += smem[1024 + g2*32 + tid];
                int mm = mg*32 + tid;
                a_all[(size_t)(256 + mm)*64 + b] = s;
                if (t >= T_READ) hist[((size_t)(t-T_READ)*K5K + 1024 + mm)*64 + b] = s;
            }
        }
        gbar(bar);
    }

    // ======== K5: out = sigmoid([h, reads]·Wo + bo), all 32 write steps ========
    {
        const int l = bk >> 3, jg = bk & 7;
        const int j0 = jg*32;
        float acc[32];
        #pragma unroll
        for (int i = 0; i < 32; ++i) acc[i] = 0.f;
        const int k0 = w*144;
        #pragma unroll 2
        for (int kk = 0; kk < 144; ++kk){
            int k = k0 + kk;
            float a = hist[((size_t)l*K5K + k)*64 + lane];
            const float* wrow = Wo + (size_t)k*D + j0;
            #pragma unroll
            for (int qq = 0; qq < 8; ++qq){
                float4 wv = *reinterpret_cast<const float4*>(wrow + qq*4);
                acc[qq*4+0] += a*wv.x; acc[qq*4+1] += a*wv.y;
                acc[qq*4+2] += a*wv.z; acc[qq*4+3] += a*wv.w;
            }
        }
        __syncthreads();
        #pragma unroll
        for (int c = 0; c < 32; ++c) smem[(w*32 + c)*64 + lane] = acc[c];
        __syncthreads();
        {
            const int b = tid >> 3, jq = tid & 7;
            float4 ov;
            float* po = (float*)&ov;
            #pragma unroll
            for (int i = 0; i < 4; ++i){
                int c = jq*4 + i;
                float s = bo[j0 + c];
                #pragma unroll
                for (int ks = 0; ks < 8; ++ks) s += smem[(ks*32 + c)*64 + b];
                po[i] = sigmoidf(s);
            }
            *reinterpret_cast<float4*>(out + ((size_t)b*L_WRITE + l)*D + j0 + jq*4) = ov;
        }
    }
}

extern "C" void kernel_launch(void* const* d_in, const int* in_sizes, int n_in,
                              void* d_out, int out_size, void* d_ws, size_t ws_size,
                              hipStream_t stream)
{
    const float* x   = (const float*)d_in[0];
    const float* Wl  = (const float*)d_in[1];
    const float* Ul  = (const float*)d_in[2];
    const float* bl  = (const float*)d_in[3];
    const float* Wh  = (const float*)d_in[4];
    const float* bh  = (const float*)d_in[5];
    const float* Wo  = (const float*)d_in[6];
    const float* bo  = (const float*)d_in[7];
    float* out = (float*)d_out;

    float* ws = (float*)d_ws;
    unsigned* bar = (unsigned*)ws;                      ws += 64;
    float* xT    = ws; ws += (size_t)T_READ*D*64;       // 2.10M
    float* a_all = ws; ws += (size_t)1408*64;           // 90K
    float* c_t   = ws; ws += (size_t)R*64;
    float* khat  = ws; ws += (size_t)B*256;
    float* scal  = ws; ws += (size_t)B*12 + 52;
    float* ea    = ws; ws += (size_t)B*256;
    float* mnorm = ws; ws += (size_t)B*N;
    float* dots  = ws; ws += (size_t)B*2*N;
    float* w_r   = ws; ws += (size_t)B*N;
    float* w_w   = ws; ws += (size_t)B*N;
    float* Mem   = ws; ws += (size_t)B*N*M;             // 4.19M
    float* hist  = ws; ws += (size_t)L_WRITE*K5K*64;    // 2.36M

    hipLaunchKernelGGL(kx_transpose, dim3(T_READ*4), dim3(256), 0, stream, x, xT);
    hipLaunchKernelGGL(k_init,       dim3(2048),     dim3(256), 0, stream, a_all, c_t, w_r, w_w, Mem, bar);
    hipLaunchKernelGGL(k_persist,    dim3(NBLK),     dim3(NTHR), 0, stream,
                       xT, Wl, Ul, bl, Wh, bh, Wo, bo,
                       a_all, c_t, khat, scal, ea, mnorm, dots,
                       w_r, w_w, Mem, hist, out, bar);
}

// Round 5
// 38717.535 us; speedup vs baseline: 1.1954x; 1.1954x over previous
//
#include <hip/hip_runtime.h>
#include <math.h>

#define B 64
#define T_READ 128
#define L_WRITE 32
#define TT 160
#define D 256
#define R 1024
#define N 512
#define M 128
#define HD 524
#define K5K 1152
#define EPS 1e-8f
#define NBLK 256
#define NTHR 512

__device__ __forceinline__ float sigmoidf(float x){ return 1.0f/(1.0f+expf(-x)); }
__device__ __forceinline__ float softplusf(float x){ return (x > 20.f) ? x : log1pf(expf(x)); }

// ---------- one-time: transpose x -> xT[t][k][b] ----------
__global__ __launch_bounds__(256) void kx_transpose(const float* __restrict__ x, float* __restrict__ xT){
    __shared__ float tile[64][65];
    const int t = blockIdx.x >> 2, k0 = (blockIdx.x & 3)*64;
    #pragma unroll
    for (int rep = 0; rep < 16; ++rep){
        int idx = rep*256 + threadIdx.x;
        int bl = idx >> 6, kl = idx & 63;
        tile[bl][kl] = x[((size_t)bl*T_READ + t)*D + k0 + kl];
    }
    __syncthreads();
    #pragma unroll
    for (int rep = 0; rep < 16; ++rep){
        int idx = rep*256 + threadIdx.x;
        int kl = idx >> 6, bl = idx & 63;
        xT[((size_t)t*D + k0 + kl)*64 + bl] = tile[bl][kl];
    }
}

// ---------- one-time: pack Wl/Ul into per-block-contiguous Wre[bk][k][16] ----------
// block bk owns z cols {q*1024 + bk*4 + i : q<4, i<4}; local col j16 = q*4+i
__global__ __launch_bounds__(256) void kpack_w(const float* __restrict__ Wl, const float* __restrict__ Ul,
                                               float* __restrict__ Wre){
    const int k = blockIdx.x;                 // 0..1407
    const float* src = (k < 384) ? (Wl + (size_t)k*4096) : (Ul + (size_t)(k-384)*4096);
    #pragma unroll
    for (int it = 0; it < 16; ++it){
        int j = it*256 + threadIdx.x;         // 0..4095
        int bk = j >> 4, r = j & 15, q = r >> 2, i = r & 3;
        Wre[((size_t)bk*1408 + k)*16 + r] = src[q*1024 + bk*4 + i];
    }
}

// ---------- one-time: pack Wh into Whre[bk][k][2] (+extras Whx[12][k]) ----------
__global__ __launch_bounds__(256) void kpack_wh(const float* __restrict__ Wh,
                                                float* __restrict__ Whre, float* __restrict__ Whx){
    const int k = blockIdx.x;                 // 0..1023
    for (int j = threadIdx.x; j < 512; j += 256)
        Whre[((size_t)(j>>1)*1024 + k)*2 + (j&1)] = Wh[(size_t)k*HD + j];
    if (threadIdx.x < 12)
        Whx[(size_t)threadIdx.x*1024 + k] = Wh[(size_t)k*HD + 512 + threadIdx.x];
}

// ---------- one-time: init all state + barrier counters ----------
__global__ void k_init(float* ht, float* c_t, float* rp, float* w_r, float* w_w,
                       float* Mem, unsigned* bar){
    int idx = blockIdx.x*blockDim.x + threadIdx.x;
    int stride = gridDim.x*blockDim.x;
    for (int i = idx; i < B*N*M; i += stride) Mem[i] = 1e-6f;
    for (int i = idx; i < R*64; i += stride){ ht[i]=0.f; c_t[i]=0.f; }
    for (int i = idx; i < 4*128*64; i += stride) rp[i] = 0.f;
    for (int i = idx; i < B*N; i += stride){ w_r[i] = 1.f/512.f; w_w[i] = 1.f/512.f; }
    if (idx < 256) bar[idx] = 0u;
}

// ---------- hierarchical device-scope grid barrier ----------
// group counters at bar[g*16] (g = bk&7), root at bar[128], release phase at bar[144]
__device__ __forceinline__ void gbar(unsigned* bar, int bk){
    __syncthreads();
    if (threadIdx.x == 0){
        __threadfence();
        unsigned* grp  = bar + ((bk & 7) << 4);
        unsigned* root = bar + 128;
        unsigned* rel  = bar + 144;
        unsigned ph = __hip_atomic_load(rel, __ATOMIC_RELAXED, __HIP_MEMORY_SCOPE_AGENT);
        unsigned a = __hip_atomic_fetch_add(grp, 1u, __ATOMIC_ACQ_REL, __HIP_MEMORY_SCOPE_AGENT);
        if (a == 31u){
            __hip_atomic_store(grp, 0u, __ATOMIC_RELAXED, __HIP_MEMORY_SCOPE_AGENT);
            unsigned r = __hip_atomic_fetch_add(root, 1u, __ATOMIC_ACQ_REL, __HIP_MEMORY_SCOPE_AGENT);
            if (r == 7u){
                __hip_atomic_store(root, 0u, __ATOMIC_RELAXED, __HIP_MEMORY_SCOPE_AGENT);
                __hip_atomic_store(rel, ph + 1u, __ATOMIC_RELEASE, __HIP_MEMORY_SCOPE_AGENT);
            } else {
                while (__hip_atomic_load(rel, __ATOMIC_ACQUIRE, __HIP_MEMORY_SCOPE_AGENT) == ph)
                    __builtin_amdgcn_s_sleep(4);
            }
        } else {
            while (__hip_atomic_load(rel, __ATOMIC_ACQUIRE, __HIP_MEMORY_SCOPE_AGENT) == ph)
                __builtin_amdgcn_s_sleep(4);
        }
        __threadfence();
    }
    __syncthreads();
}

__device__ __forceinline__ float blk_sum8(float v, volatile float* red8, int lane, int wv){
    #pragma unroll
    for (int off = 32; off; off >>= 1) v += __shfl_xor(v, off);
    if (lane == 0) red8[wv] = v;
    __syncthreads();
    float r = red8[0]+red8[1]+red8[2]+red8[3]+red8[4]+red8[5]+red8[6]+red8[7];
    __syncthreads();
    return r;
}
__device__ __forceinline__ float blk_max8(float v, volatile float* red8, int lane, int wv){
    #pragma unroll
    for (int off = 32; off; off >>= 1) v = fmaxf(v, __shfl_xor(v, off));
    if (lane == 0) red8[wv] = v;
    __syncthreads();
    float r = fmaxf(fmaxf(fmaxf(red8[0],red8[1]),fmaxf(red8[2],red8[3])),
                    fmaxf(fmaxf(red8[4],red8[5]),fmaxf(red8[6],red8[7])));
    __syncthreads();
    return r;
}

// ---------- persistent kernel ----------
__global__ __launch_bounds__(NTHR, 1) void k_persist(
    const float* __restrict__ xT, const float* __restrict__ Wre,
    const float* __restrict__ bl, const float* __restrict__ Whre, const float* __restrict__ Whx,
    const float* __restrict__ bh, const float* __restrict__ Wo, const float* __restrict__ bo,
    float* __restrict__ ht, float* __restrict__ c_t,
    float* __restrict__ khat, float* __restrict__ scal, float* __restrict__ ea,
    float* __restrict__ mnorm, float* __restrict__ dots,
    float* __restrict__ w_r, float* __restrict__ w_w,
    float* __restrict__ Mem, float* __restrict__ rp, float* __restrict__ hist,
    float* __restrict__ out, unsigned* __restrict__ bar)
{
    __shared__ float smem[16384];   // 64 KB; [0,8192)=rsum / stage misc, [8192,16384)=comb
    const int bk   = blockIdx.x;
    const int tid  = threadIdx.x;
    const int lane = tid & 63;
    const int w    = tid >> 6;

    for (int t = 0; t < TT; ++t){
        // ======== S1: stage reads; z = W·[x,reads] + U·h + b; LSTM gates ========
        {
            for (int e = tid; e < 8192; e += NTHR){
                float s = rp[e] + rp[8192+e] + rp[16384+e] + rp[24576+e];
                smem[e] = s;
                if (t > T_READ)
                    hist[((size_t)(t-1-T_READ)*K5K + 1024 + (e>>6))*64 + (e&63)] = s;
            }
            __syncthreads();
            const int r0 = bk*4;
            const int rd = (t < T_READ);
            const int kn = rd ? 176 : 144;
            const int k0 = rd ? w*176 : 256 + w*144;
            const float* wbase = Wre + ((size_t)bk*1408 + k0)*16;
            float acc[16];
            #pragma unroll
            for (int i = 0; i < 16; ++i) acc[i] = 0.f;
            #pragma unroll 4
            for (int kk = 0; kk < kn; ++kk){
                int k = k0 + kk;
                float a;
                if (k < 256)      a = xT[((size_t)t*256 + k)*64 + lane];
                else if (k < 384) a = smem[(k-256)*64 + lane];
                else              a = ht[(size_t)(k-384)*64 + lane];
                const float4* wv4 = reinterpret_cast<const float4*>(wbase + (size_t)kk*16);
                float4 w0 = wv4[0], w1 = wv4[1], w2 = wv4[2], w3 = wv4[3];
                acc[0]+=a*w0.x;  acc[1]+=a*w0.y;  acc[2]+=a*w0.z;  acc[3]+=a*w0.w;
                acc[4]+=a*w1.x;  acc[5]+=a*w1.y;  acc[6]+=a*w1.z;  acc[7]+=a*w1.w;
                acc[8]+=a*w2.x;  acc[9]+=a*w2.y;  acc[10]+=a*w2.z; acc[11]+=a*w2.w;
                acc[12]+=a*w3.x; acc[13]+=a*w3.y; acc[14]+=a*w3.z; acc[15]+=a*w3.w;
            }
            float* comb = smem + 8192;
            #pragma unroll
            for (int j = 0; j < 16; ++j) comb[(w*16 + j)*64 + lane] = acc[j];
            __syncthreads();
            if (tid < 256){
                int i = tid >> 6, b = tid & 63;
                float g4[4];
                #pragma unroll
                for (int q = 0; q < 4; ++q){
                    float s = bl[q*1024 + r0 + i];
                    #pragma unroll
                    for (int ks = 0; ks < 8; ++ks) s += comb[(ks*16 + q*4 + i)*64 + b];
                    g4[q] = s;
                }
                int ri = (r0 + i)*64 + b;
                float cn = sigmoidf(g4[1])*c_t[ri] + sigmoidf(g4[0])*tanhf(g4[2]);
                float hn = sigmoidf(g4[3])*tanhf(cn);
                c_t[ri] = cn;
                ht[ri] = hn;
                if (t >= T_READ) hist[((size_t)(t-T_READ)*K5K + r0 + i)*64 + b] = hn;
            }
        }
        gbar(bar, bk);

        // ======== S2: head params; finalize khat/scal/ea ========
        {
            const int c0 = bk*2;
            const int k0 = w*128;
            const float2* wp = reinterpret_cast<const float2*>(Whre) + ((size_t)bk*1024 + k0);
            const float*  wx = Whx + (size_t)((bk < 12) ? bk : 0)*1024 + k0;
            float a0 = 0.f, a1 = 0.f, a2 = 0.f;
            #pragma unroll 4
            for (int kk = 0; kk < 128; ++kk){
                float a = ht[(size_t)(k0+kk)*64 + lane];
                float2 wv = wp[kk];
                a0 += a*wv.x; a1 += a*wv.y; a2 += a*wx[kk];
            }
            smem[(0*8 + w)*64 + lane] = a0;
            smem[(1*8 + w)*64 + lane] = a1;
            smem[(2*8 + w)*64 + lane] = a2;
            __syncthreads();
            if (tid < 192){
                int c = tid >> 6, b = tid & 63;
                if (c < 2 || bk < 12){
                    int j = (c < 2) ? (c0 + c) : (512 + bk);
                    float v = bh[j];
                    #pragma unroll
                    for (int ks = 0; ks < 8; ++ks) v += smem[(c*8 + ks)*64 + b];
                    if (j < 128)            khat[b*256 + j] = tanhf(v);
                    else if (j < 134){ int i = j-128; scal[b*12 + i]   = (i==0)?softplusf(v):(i==1)?sigmoidf(v):(i==5)?1.f+softplusf(v):v; }
                    else if (j < 262)       khat[b*256 + 128 + (j-134)] = tanhf(v);
                    else if (j < 268){ int i = j-262; scal[b*12 + 6+i] = (i==0)?softplusf(v):(i==1)?sigmoidf(v):(i==5)?1.f+softplusf(v):v; }
                    else if (j < 396)       ea[b*256 + (j-268)]         = sigmoidf(v);
                    else                    ea[b*256 + 128 + (j-396)]   = tanhf(v);
                }
            }
        }
        gbar(bar, bk);

        // ======== S3: Mem row norms + content dots (block owns (b, nq) slice) ========
        {
            const int b = bk >> 2, nq = bk & 3;
            float2 kr = *reinterpret_cast<const float2*>(khat + b*256 + lane*2);
            float2 kw = *reinterpret_cast<const float2*>(khat + b*256 + 128 + lane*2);
            #pragma unroll 2
            for (int i = 0; i < 16; ++i){
                int n = nq*128 + w*16 + i;
                const float* mrow = Mem + ((size_t)b*N + n)*M;
                float2 mv = *reinterpret_cast<const float2*>(mrow + lane*2);
                float s2 = mv.x*mv.x + mv.y*mv.y;
                float dr = mv.x*kr.x + mv.y*kr.y;
                float dw = mv.x*kw.x + mv.y*kw.y;
                #pragma unroll
                for (int off = 32; off; off >>= 1){
                    s2 += __shfl_xor(s2, off);
                    dr += __shfl_xor(dr, off);
                    dw += __shfl_xor(dw, off);
                }
                if (lane == 0){
                    mnorm[b*N + n] = sqrtf(s2);
                    dots[(b*2+0)*N + n] = dr;
                    dots[(b*2+1)*N + n] = dw;
                }
            }
        }
        gbar(bar, bk);

        // ======== S4: addressing (blocks 0..127) ========
        if (bk < 128){
            volatile float* red8 = smem + 768;
            float* wg = smem;
            const int b = bk >> 1, head = bk & 1;
            const int n = tid;
            float kv = (n < 128) ? khat[b*256 + head*128 + n] : 0.f;
            float kn = sqrtf(blk_sum8(kv*kv, red8, lane, w));
            const float* sc = scal + b*12 + head*6;
            float beta = sc[0], gg = sc[1], gamma = sc[5];
            float s0r = sc[2], s1r = sc[3], s2r = sc[4];
            float smx = fmaxf(s0r, fmaxf(s1r, s2r));
            float e0 = expf(s0r-smx), e1 = expf(s1r-smx), e2 = expf(s2r-smx);
            float esum = e0+e1+e2;
            float s0 = e0/esum, s1 = e1/esum, s2 = e2/esum;

            float sim = dots[(b*2+head)*N + n] / (mnorm[b*N + n]*kn + EPS);
            float aa = beta * sim;
            float amax = blk_max8(aa, red8, lane, w);
            float ev = expf(aa - amax);
            float wc = ev / blk_sum8(ev, red8, lane, w);

            float* wbuf = head ? w_w : w_r;
            float wprev = wbuf[b*N + n];
            float wgv = gg*wc + (1.f - gg)*wprev;
            wg[n] = wgv; __syncthreads();
            float wsv = s0*wg[(n+1)&511] + s1*wgv + s2*wg[(n-1)&511];
            float wp2 = powf(wsv + EPS, gamma);
            float wsum = blk_sum8(wp2, red8, lane, w);
            wbuf[b*N + n] = wp2 / wsum;
        }
        gbar(bar, bk);

        // ======== S5: read (old Mem) + erase/add update, same (b, nq) ownership ========
        {
            const int b = bk >> 2, nq = bk & 3;
            if (tid < 128){
                smem[tid]       = w_r[b*N + nq*128 + tid];
                smem[128 + tid] = w_w[b*N + nq*128 + tid];
            }
            const int m = tid & 127, ns = tid >> 7;
            const float e  = ea[b*256 + m];
            const float ad = ea[b*256 + 128 + m];
            __syncthreads();
            float racc = 0.f;
            #pragma unroll 4
            for (int i2 = 0; i2 < 32; ++i2){
                int nl = i2*4 + ns;
                size_t idx = ((size_t)b*N + nq*128 + nl)*M + m;
                float v = Mem[idx];
                float wr = smem[nl], ww = smem[128+nl];
                racc += wr*v;
                Mem[idx] = v*(1.f - ww*e) + ww*ad;
            }
            __syncthreads();
            smem[256 + ns*128 + m] = racc;
            __syncthreads();
            if (tid < 128){
                float s = smem[256+tid] + smem[384+tid] + smem[512+tid] + smem[640+tid];
                rp[(size_t)nq*8192 + tid*64 + b] = s;
            }
        }
        gbar(bar, bk);
    }

    // ======== finalize last reads row of hist ========
    if (bk == 0){
        for (int e = tid; e < 8192; e += NTHR){
            float s = rp[e] + rp[8192+e] + rp[16384+e] + rp[24576+e];
            hist[((size_t)31*K5K + 1024 + (e>>6))*64 + (e&63)] = s;
        }
    }
    gbar(bar, bk);

    // ======== K5: out = sigmoid([h, reads]·Wo + bo), all 32 write steps ========
    {
        const int l = bk >> 3, jg = bk & 7;
        const int j0 = jg*32;
        float acc[32];
        #pragma unroll
        for (int i = 0; i < 32; ++i) acc[i] = 0.f;
        const int k0 = w*144;
        #pragma unroll 2
        for (int kk = 0; kk < 144; ++kk){
            int k = k0 + kk;
            float a = hist[((size_t)l*K5K + k)*64 + lane];
            const float* wrow = Wo + (size_t)k*D + j0;
            #pragma unroll
            for (int qq = 0; qq < 8; ++qq){
                float4 wv = *reinterpret_cast<const float4*>(wrow + qq*4);
                acc[qq*4+0] += a*wv.x; acc[qq*4+1] += a*wv.y;
                acc[qq*4+2] += a*wv.z; acc[qq*4+3] += a*wv.w;
            }
        }
        __syncthreads();
        #pragma unroll
        for (int c = 0; c < 32; ++c) smem[(w*32 + c)*64 + lane] = acc[c];
        __syncthreads();
        {
            const int b = tid >> 3, jq = tid & 7;
            float4 ov;
            float* po = (float*)&ov;
            #pragma unroll
            for (int i = 0; i < 4; ++i){
                int c = jq*4 + i;
                float s = bo[j0 + c];
                #pragma unroll
                for (int ks = 0; ks < 8; ++ks) s += smem[(ks*32 + c)*64 + b];
                po[i] = sigmoidf(s);
            }
            *reinterpret_cast<float4*>(out + ((size_t)b*L_WRITE + l)*D + j0 + jq*4) = ov;
        }
    }
}

extern "C" void kernel_launch(void* const* d_in, const int* in_sizes, int n_in,
                              void* d_out, int out_size, void* d_ws, size_t ws_size,
                              hipStream_t stream)
{
    const float* x   = (const float*)d_in[0];
    const float* Wl  = (const float*)d_in[1];
    const float* Ul  = (const float*)d_in[2];
    const float* bl  = (const float*)d_in[3];
    const float* Wh  = (const float*)d_in[4];
    const float* bh  = (const float*)d_in[5];
    const float* Wo  = (const float*)d_in[6];
    const float* bo  = (const float*)d_in[7];
    float* out = (float*)d_out;

    float* ws = (float*)d_ws;
    unsigned* bar = (unsigned*)ws;                      ws += 256;
    float* xT    = ws; ws += (size_t)T_READ*D*64;       // 8.4 MB
    float* Wre   = ws; ws += (size_t)1408*4096;         // 23 MB
    float* Whre  = ws; ws += (size_t)256*1024*2;        // 2 MB
    float* Whx   = ws; ws += (size_t)12*1024;
    float* ht    = ws; ws += (size_t)R*64;
    float* c_t   = ws; ws += (size_t)R*64;
    float* khat  = ws; ws += (size_t)B*256;
    float* scal  = ws; ws += (size_t)B*12 + 52;
    float* ea    = ws; ws += (size_t)B*256;
    float* mnorm = ws; ws += (size_t)B*N;
    float* dots  = ws; ws += (size_t)B*2*N;
    float* w_r   = ws; ws += (size_t)B*N;
    float* w_w   = ws; ws += (size_t)B*N;
    float* Mem   = ws; ws += (size_t)B*N*M;             // 16.8 MB
    float* rp    = ws; ws += (size_t)4*128*64;
    float* hist  = ws; ws += (size_t)L_WRITE*K5K*64;    // 9.4 MB

    hipLaunchKernelGGL(kx_transpose, dim3(T_READ*4), dim3(256), 0, stream, x, xT);
    hipLaunchKernelGGL(kpack_w,      dim3(1408),     dim3(256), 0, stream, Wl, Ul, Wre);
    hipLaunchKernelGGL(kpack_wh,     dim3(1024),     dim3(256), 0, stream, Wh, Whre, Whx);
    hipLaunchKernelGGL(k_init,       dim3(2048),     dim3(256), 0, stream, ht, c_t, rp, w_r, w_w, Mem, bar);
    hipLaunchKernelGGL(k_persist,    dim3(NBLK),     dim3(NTHR), 0, stream,
                       xT, Wre, bl, Whre, Whx, bh, Wo, bo,
                       ht, c_t, khat, scal, ea, mnorm, dots,
                       w_r, w_w, Mem, rp, hist, out, bar);
}

// Round 6
// 19873.511 us; speedup vs baseline: 2.3290x; 1.9482x over previous
//
#include <hip/hip_runtime.h>
#include <math.h>

#define B 64
#define T_READ 128
#define L_WRITE 32
#define TT 160
#define D 256
#define R 1024
#define N 512
#define M 128
#define HD 524
#define K5K 1152
#define EPS 1e-8f
#define NBLK 256
#define NTHR 512

__device__ __forceinline__ float sigmoidf(float x){ return 1.0f/(1.0f+expf(-x)); }
__device__ __forceinline__ float softplusf(float x){ return (x > 20.f) ? x : log1pf(expf(x)); }

// ---------- one-time: transpose x -> xT[t][k][b] ----------
__global__ __launch_bounds__(256) void kx_transpose(const float* __restrict__ x, float* __restrict__ xT){
    __shared__ float tile[64][65];
    const int t = blockIdx.x >> 2, k0 = (blockIdx.x & 3)*64;
    #pragma unroll
    for (int rep = 0; rep < 16; ++rep){
        int idx = rep*256 + threadIdx.x;
        int bl = idx >> 6, kl = idx & 63;
        tile[bl][kl] = x[((size_t)bl*T_READ + t)*D + k0 + kl];
    }
    __syncthreads();
    #pragma unroll
    for (int rep = 0; rep < 16; ++rep){
        int idx = rep*256 + threadIdx.x;
        int kl = idx >> 6, bl = idx & 63;
        xT[((size_t)t*D + k0 + kl)*64 + bl] = tile[bl][kl];
    }
}

// ---------- one-time: pack Wl/Ul into per-block-contiguous Wre[bk][k][16] ----------
__global__ __launch_bounds__(256) void kpack_w(const float* __restrict__ Wl, const float* __restrict__ Ul,
                                               float* __restrict__ Wre){
    const int k = blockIdx.x;                 // 0..1407
    const float* src = (k < 384) ? (Wl + (size_t)k*4096) : (Ul + (size_t)(k-384)*4096);
    #pragma unroll
    for (int it = 0; it < 16; ++it){
        int j = it*256 + threadIdx.x;         // 0..4095
        int bk = j >> 4, r = j & 15, q = r >> 2, i = r & 3;
        Wre[((size_t)bk*1408 + k)*16 + r] = src[q*1024 + bk*4 + i];
    }
}

// ---------- one-time: pack Wh into Whre[bk][k][2] (+extras Whx[12][k]) ----------
__global__ __launch_bounds__(256) void kpack_wh(const float* __restrict__ Wh,
                                                float* __restrict__ Whre, float* __restrict__ Whx){
    const int k = blockIdx.x;                 // 0..1023
    for (int j = threadIdx.x; j < 512; j += 256)
        Whre[((size_t)(j>>1)*1024 + k)*2 + (j&1)] = Wh[(size_t)k*HD + j];
    if (threadIdx.x < 12)
        Whx[(size_t)threadIdx.x*1024 + k] = Wh[(size_t)k*HD + 512 + threadIdx.x];
}

// ---------- one-time: init all state + barrier counters ----------
__global__ void k_init(float* ht, float* c_t, float* rp, float* wst,
                       float* Mem, unsigned* bar){
    int idx = blockIdx.x*blockDim.x + threadIdx.x;
    int stride = gridDim.x*blockDim.x;
    for (int i = idx; i < B*N*M; i += stride) Mem[i] = 1e-6f;
    for (int i = idx; i < R*64; i += stride){ ht[i]=0.f; c_t[i]=0.f; }
    for (int i = idx; i < 4*128*64; i += stride) rp[i] = 0.f;
    for (int i = idx; i < 2*B*N; i += stride) wst[i] = 1.f/512.f;   // parity-0, both heads
    if (idx < 256) bar[idx] = 0u;
}

// ---------- hierarchical grid barrier: relaxed polls, one acquire fence ----------
__device__ __forceinline__ void gbar(unsigned* bar, int bk){
    __syncthreads();
    if (threadIdx.x == 0){
        unsigned* grp  = bar + ((bk & 7) << 4);
        unsigned* root = bar + 128;
        unsigned* rel  = bar + 144;
        unsigned ph = __hip_atomic_load(rel, __ATOMIC_RELAXED, __HIP_MEMORY_SCOPE_AGENT);
        unsigned a = __hip_atomic_fetch_add(grp, 1u, __ATOMIC_RELEASE, __HIP_MEMORY_SCOPE_AGENT);
        if (a == 31u){
            __hip_atomic_store(grp, 0u, __ATOMIC_RELAXED, __HIP_MEMORY_SCOPE_AGENT);
            unsigned r = __hip_atomic_fetch_add(root, 1u, __ATOMIC_RELEASE, __HIP_MEMORY_SCOPE_AGENT);
            if (r == 7u){
                __hip_atomic_store(root, 0u, __ATOMIC_RELAXED, __HIP_MEMORY_SCOPE_AGENT);
                __hip_atomic_store(rel, ph + 1u, __ATOMIC_RELEASE, __HIP_MEMORY_SCOPE_AGENT);
            } else {
                while (__hip_atomic_load(rel, __ATOMIC_RELAXED, __HIP_MEMORY_SCOPE_AGENT) == ph)
                    __builtin_amdgcn_s_sleep(8);
            }
        } else {
            while (__hip_atomic_load(rel, __ATOMIC_RELAXED, __HIP_MEMORY_SCOPE_AGENT) == ph)
                __builtin_amdgcn_s_sleep(8);
        }
        __builtin_amdgcn_fence(__ATOMIC_ACQUIRE, "agent");
    }
    __syncthreads();
}

__device__ __forceinline__ float blk_sum8(float v, volatile float* red8, int lane, int wv){
    #pragma unroll
    for (int off = 32; off; off >>= 1) v += __shfl_xor(v, off);
    if (lane == 0) red8[wv] = v;
    __syncthreads();
    float r = red8[0]+red8[1]+red8[2]+red8[3]+red8[4]+red8[5]+red8[6]+red8[7];
    __syncthreads();
    return r;
}
__device__ __forceinline__ float blk_max8(float v, volatile float* red8, int lane, int wv){
    #pragma unroll
    for (int off = 32; off; off >>= 1) v = fmaxf(v, __shfl_xor(v, off));
    if (lane == 0) red8[wv] = v;
    __syncthreads();
    float r = fmaxf(fmaxf(fmaxf(red8[0],red8[1]),fmaxf(red8[2],red8[3])),
                    fmaxf(fmaxf(red8[4],red8[5]),fmaxf(red8[6],red8[7])));
    __syncthreads();
    return r;
}

// ---------- persistent kernel: 4 grid barriers per step ----------
__global__ __launch_bounds__(NTHR, 1) void k_persist(
    const float* __restrict__ xT, const float* __restrict__ Wre,
    const float* __restrict__ bl, const float* __restrict__ Whre, const float* __restrict__ Whx,
    const float* __restrict__ bh, const float* __restrict__ Wo, const float* __restrict__ bo,
    float* __restrict__ ht, float* __restrict__ c_t,
    float* __restrict__ khat, float* __restrict__ scal, float* __restrict__ ea,
    float* __restrict__ mnorm, float* __restrict__ dots,
    float* __restrict__ wst, float* __restrict__ Mem, float* __restrict__ rp,
    float* __restrict__ hist, float* __restrict__ out, unsigned* __restrict__ bar)
{
    __shared__ float smem[16384];   // 64 KB
    // logical block id: siblings (b, nq=0..3) co-resident on one XCD
    const int bk   = ((blockIdx.x & 7) << 5) | (blockIdx.x >> 3);
    const int tid  = threadIdx.x;
    const int lane = tid & 63;
    const int w    = tid >> 6;

    for (int t = 0; t < TT; ++t){
        // ======== S1: stage reads; z = W·[x,reads] + U·h + b; LSTM gates ========
        {
            for (int e = tid; e < 8192; e += NTHR){
                float s = rp[e] + rp[8192+e] + rp[16384+e] + rp[24576+e];
                smem[e] = s;
                if (t > T_READ)
                    hist[((size_t)(t-1-T_READ)*K5K + 1024 + (e>>6))*64 + (e&63)] = s;
            }
            __syncthreads();
            const int r0 = bk*4;
            const int rd = (t < T_READ);
            const int kn = rd ? 176 : 144;
            const int k0 = rd ? w*176 : 256 + w*144;
            const float* wbase = Wre + ((size_t)bk*1408 + k0)*16;
            float acc[16];
            #pragma unroll
            for (int i = 0; i < 16; ++i) acc[i] = 0.f;
            #pragma unroll 4
            for (int kk = 0; kk < kn; ++kk){
                int k = k0 + kk;
                float a;
                if (k < 256)      a = xT[((size_t)t*256 + k)*64 + lane];
                else if (k < 384) a = smem[(k-256)*64 + lane];
                else              a = ht[(size_t)(k-384)*64 + lane];
                const float4* wv4 = reinterpret_cast<const float4*>(wbase + (size_t)kk*16);
                float4 w0 = wv4[0], w1 = wv4[1], w2 = wv4[2], w3 = wv4[3];
                acc[0]+=a*w0.x;  acc[1]+=a*w0.y;  acc[2]+=a*w0.z;  acc[3]+=a*w0.w;
                acc[4]+=a*w1.x;  acc[5]+=a*w1.y;  acc[6]+=a*w1.z;  acc[7]+=a*w1.w;
                acc[8]+=a*w2.x;  acc[9]+=a*w2.y;  acc[10]+=a*w2.z; acc[11]+=a*w2.w;
                acc[12]+=a*w3.x; acc[13]+=a*w3.y; acc[14]+=a*w3.z; acc[15]+=a*w3.w;
            }
            float* comb = smem + 8192;
            #pragma unroll
            for (int j = 0; j < 16; ++j) comb[(w*16 + j)*64 + lane] = acc[j];
            __syncthreads();
            if (tid < 256){
                int i = tid >> 6, b = tid & 63;
                float g4[4];
                #pragma unroll
                for (int q = 0; q < 4; ++q){
                    float s = bl[q*1024 + r0 + i];
                    #pragma unroll
                    for (int ks = 0; ks < 8; ++ks) s += comb[(ks*16 + q*4 + i)*64 + b];
                    g4[q] = s;
                }
                int ri = (r0 + i)*64 + b;
                float cn = sigmoidf(g4[1])*c_t[ri] + sigmoidf(g4[0])*tanhf(g4[2]);
                float hn = sigmoidf(g4[3])*tanhf(cn);
                c_t[ri] = cn;
                ht[ri] = hn;
                if (t >= T_READ) hist[((size_t)(t-T_READ)*K5K + r0 + i)*64 + b] = hn;
            }
        }
        gbar(bar, bk);

        // ======== S2: head params; finalize khat/scal/ea ========
        {
            const int c0 = bk*2;
            const int k0 = w*128;
            const float2* wp = reinterpret_cast<const float2*>(Whre) + ((size_t)bk*1024 + k0);
            const float*  wx = Whx + (size_t)((bk < 12) ? bk : 0)*1024 + k0;
            float a0 = 0.f, a1 = 0.f, a2 = 0.f;
            #pragma unroll 4
            for (int kk = 0; kk < 128; ++kk){
                float a = ht[(size_t)(k0+kk)*64 + lane];
                float2 wv = wp[kk];
                a0 += a*wv.x; a1 += a*wv.y; a2 += a*wx[kk];
            }
            smem[(0*8 + w)*64 + lane] = a0;
            smem[(1*8 + w)*64 + lane] = a1;
            smem[(2*8 + w)*64 + lane] = a2;
            __syncthreads();
            if (tid < 192){
                int c = tid >> 6, b = tid & 63;
                if (c < 2 || bk < 12){
                    int j = (c < 2) ? (c0 + c) : (512 + bk);
                    float v = bh[j];
                    #pragma unroll
                    for (int ks = 0; ks < 8; ++ks) v += smem[(c*8 + ks)*64 + b];
                    if (j < 128)            khat[b*256 + j] = tanhf(v);
                    else if (j < 134){ int i = j-128; scal[b*12 + i]   = (i==0)?softplusf(v):(i==1)?sigmoidf(v):(i==5)?1.f+softplusf(v):v; }
                    else if (j < 262)       khat[b*256 + 128 + (j-134)] = tanhf(v);
                    else if (j < 268){ int i = j-262; scal[b*12 + 6+i] = (i==0)?softplusf(v):(i==1)?sigmoidf(v):(i==5)?1.f+softplusf(v):v; }
                    else if (j < 396)       ea[b*256 + (j-268)]         = sigmoidf(v);
                    else                    ea[b*256 + 128 + (j-396)]   = tanhf(v);
                }
            }
        }
        gbar(bar, bk);

        // ======== S3: Mem row norms + content dots (block owns (b, nq) slice) ========
        {
            const int b = bk >> 2, nq = bk & 3;
            float2 kr = *reinterpret_cast<const float2*>(khat + b*256 + lane*2);
            float2 kw = *reinterpret_cast<const float2*>(khat + b*256 + 128 + lane*2);
            #pragma unroll 2
            for (int i = 0; i < 16; ++i){
                int n = nq*128 + w*16 + i;
                const float* mrow = Mem + ((size_t)b*N + n)*M;
                float2 mv = *reinterpret_cast<const float2*>(mrow + lane*2);
                float s2 = mv.x*mv.x + mv.y*mv.y;
                float dr = mv.x*kr.x + mv.y*kr.y;
                float dw = mv.x*kw.x + mv.y*kw.y;
                #pragma unroll
                for (int off = 32; off; off >>= 1){
                    s2 += __shfl_xor(s2, off);
                    dr += __shfl_xor(dr, off);
                    dw += __shfl_xor(dw, off);
                }
                if (lane == 0){
                    mnorm[b*N + n] = sqrtf(s2);
                    dots[(b*2+0)*N + n] = dr;
                    dots[(b*2+1)*N + n] = dw;
                }
            }
        }
        gbar(bar, bk);

        // ======== S4+S5 fused: redundant addressing per sibling; Mem update; reads ========
        {
            const int b = bk >> 2, nq = bk & 3;
            float* wr_s = smem;                 // [512]
            float* ww_s = smem + 512;           // [512]
            float* wg   = smem + 1024;          // [512]
            volatile float* red8 = smem + 1536; // [8]
            const int n = tid;
            #pragma unroll 1
            for (int head = 0; head < 2; ++head){
                float kv = (n < 128) ? khat[b*256 + head*128 + n] : 0.f;
                float kn = sqrtf(blk_sum8(kv*kv, red8, lane, w));
                const float* sc = scal + b*12 + head*6;
                float beta = sc[0], gg = sc[1], gamma = sc[5];
                float s0r = sc[2], s1r = sc[3], s2r = sc[4];
                float smx = fmaxf(s0r, fmaxf(s1r, s2r));
                float e0 = expf(s0r-smx), e1 = expf(s1r-smx), e2 = expf(s2r-smx);
                float esum = e0+e1+e2;
                float s0 = e0/esum, s1 = e1/esum, s2 = e2/esum;

                float sim = dots[(b*2+head)*N + n] / (mnorm[b*N + n]*kn + EPS);
                float aa = beta * sim;
                float amax = blk_max8(aa, red8, lane, w);
                float ev = expf(aa - amax);
                float wc = ev / blk_sum8(ev, red8, lane, w);

                const float* wpr = wst + ((size_t)((t&1)*2 + head))*(B*N);
                float*       wnx = wst + ((size_t)(((t+1)&1)*2 + head))*(B*N);
                float wprev = wpr[b*N + n];
                float wgv = gg*wc + (1.f - gg)*wprev;
                wg[n] = wgv; __syncthreads();
                float wsv = s0*wg[(n+1)&511] + s1*wgv + s2*wg[(n-1)&511];
                float wp2 = powf(wsv + EPS, gamma);
                float wsum = blk_sum8(wp2, red8, lane, w);
                float wv = wp2 / wsum;
                (head ? ww_s : wr_s)[n] = wv;
                if (nq == 0) wnx[b*N + n] = wv;
                __syncthreads();
            }
            // S5 on own (b, nq) slice using LDS weightings
            const int m = tid & 127, ns = tid >> 7;
            const float e  = ea[b*256 + m];
            const float ad = ea[b*256 + 128 + m];
            float racc = 0.f;
            #pragma unroll 4
            for (int i2 = 0; i2 < 32; ++i2){
                int nn = nq*128 + i2*4 + ns;
                size_t idx = ((size_t)b*N + nn)*M + m;
                float v = Mem[idx];
                float wr = wr_s[nn], ww = ww_s[nn];
                racc += wr*v;
                Mem[idx] = v*(1.f - ww*e) + ww*ad;
            }
            __syncthreads();
            smem[1600 + ns*128 + m] = racc;
            __syncthreads();
            if (tid < 128){
                float s = smem[1600+tid] + smem[1728+tid] + smem[1856+tid] + smem[1984+tid];
                rp[(size_t)nq*8192 + tid*64 + b] = s;
            }
        }
        gbar(bar, bk);
    }

    // ======== finalize last reads row of hist ========
    if (bk == 0){
        for (int e = tid; e < 8192; e += NTHR){
            float s = rp[e] + rp[8192+e] + rp[16384+e] + rp[24576+e];
            hist[((size_t)31*K5K + 1024 + (e>>6))*64 + (e&63)] = s;
        }
    }
    gbar(bar, bk);

    // ======== K5: out = sigmoid([h, reads]·Wo + bo), all 32 write steps ========
    {
        const int l = bk >> 3, jg = bk & 7;
        const int j0 = jg*32;
        float acc[32];
        #pragma unroll
        for (int i = 0; i < 32; ++i) acc[i] = 0.f;
        const int k0 = w*144;
        #pragma unroll 2
        for (int kk = 0; kk < 144; ++kk){
            int k = k0 + kk;
            float a = hist[((size_t)l*K5K + k)*64 + lane];
            const float* wrow = Wo + (size_t)k*D + j0;
            #pragma unroll
            for (int qq = 0; qq < 8; ++qq){
                float4 wv = *reinterpret_cast<const float4*>(wrow + qq*4);
                acc[qq*4+0] += a*wv.x; acc[qq*4+1] += a*wv.y;
                acc[qq*4+2] += a*wv.z; acc[qq*4+3] += a*wv.w;
            }
        }
        __syncthreads();
        #pragma unroll
        for (int c = 0; c < 32; ++c) smem[(w*32 + c)*64 + lane] = acc[c];
        __syncthreads();
        {
            const int b = tid >> 3, jq = tid & 7;
            float4 ov;
            float* po = (float*)&ov;
            #pragma unroll
            for (int i = 0; i < 4; ++i){
                int c = jq*4 + i;
                float s = bo[j0 + c];
                #pragma unroll
                for (int ks = 0; ks < 8; ++ks) s += smem[(ks*32 + c)*64 + b];
                po[i] = sigmoidf(s);
            }
            *reinterpret_cast<float4*>(out + ((size_t)b*L_WRITE + l)*D + j0 + jq*4) = ov;
        }
    }
}

extern "C" void kernel_launch(void* const* d_in, const int* in_sizes, int n_in,
                              void* d_out, int out_size, void* d_ws, size_t ws_size,
                              hipStream_t stream)
{
    const float* x   = (const float*)d_in[0];
    const float* Wl  = (const float*)d_in[1];
    const float* Ul  = (const float*)d_in[2];
    const float* bl  = (const float*)d_in[3];
    const float* Wh  = (const float*)d_in[4];
    const float* bh  = (const float*)d_in[5];
    const float* Wo  = (const float*)d_in[6];
    const float* bo  = (const float*)d_in[7];
    float* out = (float*)d_out;

    float* ws = (float*)d_ws;
    unsigned* bar = (unsigned*)ws;                      ws += 256;
    float* xT    = ws; ws += (size_t)T_READ*D*64;       // 8.4 MB
    float* Wre   = ws; ws += (size_t)1408*4096;         // 23 MB
    float* Whre  = ws; ws += (size_t)256*1024*2;        // 2 MB
    float* Whx   = ws; ws += (size_t)12*1024;
    float* ht    = ws; ws += (size_t)R*64;
    float* c_t   = ws; ws += (size_t)R*64;
    float* khat  = ws; ws += (size_t)B*256;
    float* scal  = ws; ws += (size_t)B*12 + 52;
    float* ea    = ws; ws += (size_t)B*256;
    float* mnorm = ws; ws += (size_t)B*N;
    float* dots  = ws; ws += (size_t)B*2*N;
    float* wst   = ws; ws += (size_t)4*B*N;             // double-buffered w (parity x head)
    float* Mem   = ws; ws += (size_t)B*N*M;             // 16.8 MB
    float* rp    = ws; ws += (size_t)4*128*64;
    float* hist  = ws; ws += (size_t)L_WRITE*K5K*64;    // 9.4 MB

    hipLaunchKernelGGL(kx_transpose, dim3(T_READ*4), dim3(256), 0, stream, x, xT);
    hipLaunchKernelGGL(kpack_w,      dim3(1408),     dim3(256), 0, stream, Wl, Ul, Wre);
    hipLaunchKernelGGL(kpack_wh,     dim3(1024),     dim3(256), 0, stream, Wh, Whre, Whx);
    hipLaunchKernelGGL(k_init,       dim3(2048),     dim3(256), 0, stream, ht, c_t, rp, wst, Mem, bar);
    hipLaunchKernelGGL(k_persist,    dim3(NBLK),     dim3(NTHR), 0, stream,
                       xT, Wre, bl, Whre, Whx, bh, Wo, bo,
                       ht, c_t, khat, scal, ea, mnorm, dots,
                       wst, Mem, rp, hist, out, bar);
}